// Round 1
// baseline (61435.406 us; speedup 1.0000x reference)
//
#include <hip/hip_runtime.h>
#include <stdint.h>

#define TT 2048
#define HH 256
#define BB 128

typedef __attribute__((ext_vector_type(8))) short short8;   // 8 x bf16 (4 VGPRs)
typedef __attribute__((ext_vector_type(4))) float f32x4;    // 4 x f32 acc

__device__ __forceinline__ unsigned short f2bf(float f) {
  union { float f; unsigned int u; } v; v.f = f;
  unsigned int r = v.u + 0x7fffu + ((v.u >> 16) & 1u);   // RNE
  return (unsigned short)(r >> 16);
}
__device__ __forceinline__ float sigm(float x) { return 1.0f / (1.0f + __expf(-x)); }
__device__ __forceinline__ float tanh_f(float x) { return 1.0f - 2.0f / (1.0f + __expf(2.0f * x)); }

// ---------------- prep: weight bf16 conversion, bias sums, zero state ----------------
__global__ void prep_kernel(const float* __restrict__ whh0, const float* __restrict__ wih1,
                            const float* __restrict__ whh1,
                            const float* __restrict__ bih0, const float* __restrict__ bhh0,
                            const float* __restrict__ bih1, const float* __restrict__ bhh1,
                            unsigned short* __restrict__ whh0b, unsigned short* __restrict__ wih1b,
                            unsigned short* __restrict__ whh1b,
                            float* __restrict__ bsum0, float* __restrict__ bsum1,
                            float* __restrict__ zero_span) {
  int i = blockIdx.x * blockDim.x + threadIdx.x;   // 262144 threads exactly
  if (i < 262144) {
    whh0b[i] = f2bf(whh0[i]);
    wih1b[i] = f2bf(wih1[i]);
    whh1b[i] = f2bf(whh1[i]);
  }
  if (i < 1024) bsum0[i] = bih0[i] + bhh0[i];
  else if (i < 2048) { int j = i - 1024; bsum1[j] = bih1[j] + bhh1[j]; }
  if (i < 163840) zero_span[i] = 0.0f;   // h1/c1/h2/c2 state + pooled
}

// ---------------- fused recurrence: blocks 0-7 = layer0 chunk ca, 8-15 = layer1 chunk ca-1 ----
// Per WG: 16 samples, 16 waves; wave w owns hidden units [16w,16w+16).
// W slices live in VGPRs as bf16 B-fragments. h(t) in LDS (double buffer, XOR swizzle).
__global__ __launch_bounds__(1024) void rec_fused(
    const float* __restrict__ x,
    const unsigned short* __restrict__ whh0b,
    const float* __restrict__ wih0,          // [1024] fp32 (input dim == 1)
    const float* __restrict__ bsum0,
    const unsigned short* __restrict__ whh1b,
    const unsigned short* __restrict__ wih1b,
    const float* __restrict__ bsum1,
    const int* __restrict__ lengths,
    float* __restrict__ h1state, float* __restrict__ c1state,
    float* __restrict__ h2state, float* __restrict__ c2state,
    float* __restrict__ pooled,
    unsigned short* __restrict__ h1buf,      // 2 chunk buffers [B][TC][256] bf16
    int ca, int TC, int NC)
{
  __shared__ unsigned short hbuf[2][16 * 256];   // 16KB: h tile double buffer
  const int tid  = threadIdx.x;
  const int lane = tid & 63;
  const int w    = tid >> 6;
  const int l15  = lane & 15;
  const int l4   = lane >> 4;
  const int unit = w * 16 + l15;               // hidden unit owned (N-dim of D)
  const bool L1  = (blockIdx.x >= 8);
  const int b0   = (L1 ? (int)blockIdx.x - 8 : (int)blockIdx.x) * 16;
  const int chunk = L1 ? ca - 1 : ca;
  if (L1 ? (chunk < 0) : (chunk >= NC)) return;
  const int t0 = chunk * TC;
  const size_t BUFSZ = (size_t)BB * TC * HH;

  char* lds = (char*)&hbuf[0][0];

  // -- register-resident weights: B-frag lane l holds W[row = gt*256+unit][kk*32 + 8*l4 .. +8]
  short8 whh[4][8];
  short8 wih[4][8];
  const unsigned short* WA = L1 ? whh1b : whh0b;
#pragma unroll
  for (int gt = 0; gt < 4; ++gt)
#pragma unroll
    for (int kk = 0; kk < 8; ++kk)
      whh[gt][kk] = *(const short8*)(WA + (size_t)(gt * 256 + unit) * 256 + kk * 32 + l4 * 8);
  if (L1) {
#pragma unroll
    for (int gt = 0; gt < 4; ++gt)
#pragma unroll
      for (int kk = 0; kk < 8; ++kk)
        wih[gt][kk] = *(const short8*)(wih1b + (size_t)(gt * 256 + unit) * 256 + kk * 32 + l4 * 8);
  }

  float wih0_l[4], bs_l[4];
#pragma unroll
  for (int gt = 0; gt < 4; ++gt) {
    bs_l[gt]   = (L1 ? bsum1 : bsum0)[gt * 256 + unit];
    wih0_l[gt] = L1 ? 0.0f : wih0[gt * 256 + unit];
  }

  float* cst = L1 ? c2state : c1state;
  float* hst = L1 ? h2state : h1state;
  float c_[4], psum[4], lasth[4];
  int   len_[4];
#pragma unroll
  for (int r = 0; r < 4; ++r) {
    const int sr = l4 * 4 + r;
    const int b  = b0 + sr;
    c_[r]    = cst[(size_t)b * HH + unit];
    psum[r]  = 0.0f;
    lasth[r] = 0.0f;
    len_[r]  = lengths[b];
    float hv = hst[(size_t)b * HH + unit];
    const int off = ((sr * 512) + unit * 2) ^ ((sr & 7) << 4);   // buf 0
    *(unsigned short*)(lds + off) = f2bf(hv);
  }
  __syncthreads();

  const unsigned short* h1r = h1buf + (size_t)(chunk & 1) * BUFSZ;   // L1 reads its chunk
  unsigned short*       h1w = h1buf + (size_t)(chunk & 1) * BUFSZ;   // L0 writes its chunk

  // prefetch first layer-1 input tile (A-frag: lane holds h1[b0+l15][kk*32+8*l4 ..+8])
  short8 af1[8];
  if (L1) {
#pragma unroll
    for (int kk = 0; kk < 8; ++kk)
      af1[kk] = *(const short8*)(h1r + ((size_t)(b0 + l15) * TC + 0) * HH + kk * 32 + l4 * 8);
  }

  for (int tl = 0; tl < TC; ++tl) {
    const int p = tl & 1;
    char* ldsr = lds + p * 8192;
    char* ldsw = lds + (p ^ 1) * 8192;

    // A-frags of h(t-1) from LDS (swizzled, conflict-free b128)
    short8 af[8];
#pragma unroll
    for (int kk = 0; kk < 8; ++kk) {
      const int off = (l15 * 512 + kk * 64 + l4 * 16) ^ ((l15 & 7) << 4);
      af[kk] = *(const short8*)(ldsr + off);
    }

    f32x4 zv = {0.f, 0.f, 0.f, 0.f};
    f32x4 acc[4];
#pragma unroll
    for (int gt = 0; gt < 4; ++gt) acc[gt] = zv;

#pragma unroll
    for (int gt = 0; gt < 4; ++gt)
#pragma unroll
      for (int kk = 0; kk < 8; ++kk)
        acc[gt] = __builtin_amdgcn_mfma_f32_16x16x32_bf16(af[kk], whh[gt][kk], acc[gt], 0, 0, 0);

    if (L1) {
#pragma unroll
      for (int gt = 0; gt < 4; ++gt)
#pragma unroll
        for (int kk = 0; kk < 8; ++kk)
          acc[gt] = __builtin_amdgcn_mfma_f32_16x16x32_bf16(af1[kk], wih[gt][kk], acc[gt], 0, 0, 0);
      if (tl + 1 < TC) {     // prefetch next h1 tile (independent of recurrence)
#pragma unroll
        for (int kk = 0; kk < 8; ++kk)
          af1[kk] = *(const short8*)(h1r + ((size_t)(b0 + l15) * TC + (tl + 1)) * HH + kk * 32 + l4 * 8);
      }
    }

    const int t = t0 + tl;
#pragma unroll
    for (int r = 0; r < 4; ++r) {
      const int sr = l4 * 4 + r;            // D row = sample
      const int b  = b0 + sr;
      float pi = acc[0][r] + bs_l[0];
      float pf = acc[1][r] + bs_l[1];
      float pg = acc[2][r] + bs_l[2];
      float po = acc[3][r] + bs_l[3];
      if (!L1) {
        const float xv = x[(size_t)b * TT + t];
        pi += xv * wih0_l[0]; pf += xv * wih0_l[1];
        pg += xv * wih0_l[2]; po += xv * wih0_l[3];
      }
      const float ig = sigm(pi), fg = sigm(pf), gg = tanh_f(pg), og = sigm(po);
      const float cn = fg * c_[r] + ig * gg;
      c_[r] = cn;
      const float hn = og * tanh_f(cn);
      lasth[r] = hn;
      const unsigned short hb = f2bf(hn);
      const int off = (sr * 512 + unit * 2) ^ ((sr & 7) << 4);
      *(unsigned short*)(ldsw + off) = hb;
      if (!L1) {
        h1w[((size_t)b * TC + tl) * HH + unit] = hb;
      } else if (t < len_[r]) {
        psum[r] += hn;
      }
    }
    __syncthreads();
  }

  // state writeback (h rounded to bf16 to match intra-chunk trajectory exactly)
#pragma unroll
  for (int r = 0; r < 4; ++r) {
    const int b = b0 + l4 * 4 + r;
    union { unsigned int u; float f; } v; v.u = ((unsigned int)f2bf(lasth[r])) << 16;
    hst[(size_t)b * HH + unit] = v.f;
    cst[(size_t)b * HH + unit] = c_[r];
    if (L1) pooled[(size_t)b * HH + unit] += psum[r];
  }
}

// ---------------- epilogue: masked-mean already accumulated; apply 1/len and linear ----------
__global__ void out_kernel(const float* __restrict__ pooled, const int* __restrict__ lengths,
                           const float* __restrict__ wlin, const float* __restrict__ blin,
                           float* __restrict__ out) {
  const int b = blockIdx.x;
  const int lane = threadIdx.x;   // 64
  float s[7];
#pragma unroll
  for (int c = 0; c < 7; ++c) s[c] = 0.f;
  for (int k = lane; k < 256; k += 64) {
    const float pv = pooled[b * 256 + k];
#pragma unroll
    for (int c = 0; c < 7; ++c) s[c] += pv * wlin[c * 256 + k];
  }
#pragma unroll
  for (int c = 0; c < 7; ++c) {
#pragma unroll
    for (int off = 32; off > 0; off >>= 1) s[c] += __shfl_down(s[c], off);
  }
  if (lane == 0) {
    const float inv = 1.0f / (float)lengths[b];
#pragma unroll
    for (int c = 0; c < 7; ++c) out[b * 7 + c] = s[c] * inv + blin[c];
  }
}

extern "C" void kernel_launch(void* const* d_in, const int* in_sizes, int n_in,
                              void* d_out, int out_size, void* d_ws, size_t ws_size,
                              hipStream_t stream) {
  const float* x      = (const float*)d_in[0];
  const int*   lengths= (const int*)d_in[1];
  const float* W_ih0  = (const float*)d_in[2];
  const float* W_hh0  = (const float*)d_in[3];
  const float* b_ih0  = (const float*)d_in[4];
  const float* b_hh0  = (const float*)d_in[5];
  const float* W_ih1  = (const float*)d_in[6];
  const float* W_hh1  = (const float*)d_in[7];
  const float* b_ih1  = (const float*)d_in[8];
  const float* b_hh1  = (const float*)d_in[9];
  const float* W_lin  = (const float*)d_in[10];
  const float* b_lin  = (const float*)d_in[11];
  float* out = (float*)d_out;

  char* ws = (char*)d_ws;
  unsigned short* whh0b = (unsigned short*)(ws + 0);
  unsigned short* wih1b = (unsigned short*)(ws + 524288);
  unsigned short* whh1b = (unsigned short*)(ws + 1048576);
  float* bsum0   = (float*)(ws + 1572864);
  float* bsum1   = (float*)(ws + 1576960);
  float* h1state = (float*)(ws + 1581056);   // start of the zeroed span
  float* c1state = (float*)(ws + 1712128);
  float* h2state = (float*)(ws + 1843200);
  float* c2state = (float*)(ws + 1974272);
  float* pooled  = (float*)(ws + 2105344);
  unsigned short* h1buf = (unsigned short*)(ws + 2236416);

  int TC = 128;   // chunk length: 17 launches, 2x8.4MB h1 buffers
  while ((size_t)2236416 + 2ull * BB * TC * HH * sizeof(unsigned short) > ws_size && TC > 32)
    TC >>= 1;
  const int NC = TT / TC;

  prep_kernel<<<dim3(1024), dim3(256), 0, stream>>>(
      W_hh0, W_ih1, W_hh1, b_ih0, b_hh0, b_ih1, b_hh1,
      whh0b, wih1b, whh1b, bsum0, bsum1, h1state);

  for (int ca = 0; ca <= NC; ++ca) {
    rec_fused<<<dim3(16), dim3(1024), 0, stream>>>(
        x, whh0b, W_ih0, bsum0, whh1b, wih1b, bsum1, lengths,
        h1state, c1state, h2state, c2state, pooled, h1buf, ca, TC, NC);
  }

  out_kernel<<<dim3(128), dim3(64), 0, stream>>>(pooled, lengths, W_lin, b_lin, out);
}

// Round 2
// 32168.695 us; speedup vs baseline: 1.9098x; 1.9098x over previous
//
#include <hip/hip_runtime.h>
#include <stdint.h>

#define TT 2048
#define HH 256
#define BB 128

typedef __attribute__((ext_vector_type(8))) short short8;   // 8 x bf16 (4 VGPRs)
typedef __attribute__((ext_vector_type(4))) float f32x4;    // 4 x f32 acc

__device__ __forceinline__ unsigned short f2bf(float f) {
  union { float f; unsigned int u; } v; v.f = f;
  unsigned int r = v.u + 0x7fffu + ((v.u >> 16) & 1u);   // RNE
  return (unsigned short)(r >> 16);
}
__device__ __forceinline__ float sigm(float x) { return 1.0f / (1.0f + __expf(-x)); }
__device__ __forceinline__ float tanh_f(float x) { return 1.0f - 2.0f / (1.0f + __expf(2.0f * x)); }

// ---------------- prep: weight bf16 conversion, bias sums, zero state+counters ----------------
__global__ void prep_kernel(const float* __restrict__ whh0, const float* __restrict__ wih1,
                            const float* __restrict__ whh1,
                            const float* __restrict__ bih0, const float* __restrict__ bhh0,
                            const float* __restrict__ bih1, const float* __restrict__ bhh1,
                            unsigned short* __restrict__ whh0b, unsigned short* __restrict__ wih1b,
                            unsigned short* __restrict__ whh1b,
                            float* __restrict__ bsum0, float* __restrict__ bsum1,
                            float* __restrict__ zero_span) {
  int i = blockIdx.x * blockDim.x + threadIdx.x;   // 262144 threads exactly
  if (i < 262144) {
    whh0b[i] = f2bf(whh0[i]);
    wih1b[i] = f2bf(wih1[i]);
    whh1b[i] = f2bf(whh1[i]);
  }
  if (i < 1024) bsum0[i] = bih0[i] + bhh0[i];
  else if (i < 2048) { int j = i - 1024; bsum1[j] = bih1[j] + bhh1[j]; }
  if (i < 164096) zero_span[i] = 0.0f;   // h1/c1/h2/c2 state + pooled + step counters
}

// ---------------- xg1 precompute: xg[tl][b][g] = h1[b][tl][:] . wih1[g][:] -------------------
// grid = 16 * (TC/16); block 512 = 8 waves; wave w covers 64 gate rows (4 N-tiles).
__global__ __launch_bounds__(512, 2) void xg_gemm(
    const unsigned short* __restrict__ h1buf,   // [B][TC][256] bf16 (chunk ca-1)
    const unsigned short* __restrict__ wih1b,   // [1024][256] bf16
    float* __restrict__ xg, int TC)
{
  const int lane = threadIdx.x & 63;
  const int w = threadIdx.x >> 6;
  const int l15 = lane & 15, l4 = lane >> 4;
  const int bg = blockIdx.x & 7;
  const int gh = (blockIdx.x >> 3) & 1;
  const int ts = blockIdx.x >> 4;
  const int b0 = bg * 16;
  const int g0 = gh * 512 + w * 64;

  short8 bf[4][8];
#pragma unroll
  for (int nt = 0; nt < 4; ++nt)
#pragma unroll
    for (int kk = 0; kk < 8; ++kk)
      bf[nt][kk] = *(const short8*)(wih1b + (size_t)(g0 + nt * 16 + l15) * 256 + kk * 32 + l4 * 8);

  for (int tl = ts * 16; tl < ts * 16 + 16; ++tl) {
    short8 af[8];
#pragma unroll
    for (int kk = 0; kk < 8; ++kk)
      af[kk] = *(const short8*)(h1buf + ((size_t)(b0 + l15) * TC + tl) * 256 + kk * 32 + l4 * 8);
    f32x4 z = {0.f, 0.f, 0.f, 0.f};
    f32x4 acc[4];
#pragma unroll
    for (int nt = 0; nt < 4; ++nt) acc[nt] = z;
#pragma unroll
    for (int nt = 0; nt < 4; ++nt)
#pragma unroll
      for (int kk = 0; kk < 8; ++kk)
        acc[nt] = __builtin_amdgcn_mfma_f32_16x16x32_bf16(af[kk], bf[nt][kk], acc[nt], 0, 0, 0);
#pragma unroll
    for (int nt = 0; nt < 4; ++nt)
#pragma unroll
      for (int r = 0; r < 4; ++r)
        xg[((size_t)tl * BB + b0 + l4 * 4 + r) * 1024 + g0 + nt * 16 + l15] = acc[nt][r];
  }
}

// ---------------- recurrence: 32 WGs = [half][layer][bg]; 8 waves x 16 units each half ------
// Halves exchange h through global memory with per-wave release/acquire step counters.
__global__ __launch_bounds__(512, 2) void rec2(
    const float* __restrict__ x,
    const unsigned short* __restrict__ whh0b, const float* __restrict__ wih0,
    const float* __restrict__ bsum0,
    const unsigned short* __restrict__ whh1b, const float* __restrict__ bsum1,
    const float* __restrict__ xg,              // [TC][B][1024] f32 (L1 chunk ca-1)
    const int* __restrict__ lengths,
    float* __restrict__ h1state, float* __restrict__ c1state,
    float* __restrict__ h2state, float* __restrict__ c2state,
    float* __restrict__ pooled,
    unsigned short* __restrict__ h1buf,        // [B][TC][256] bf16
    unsigned short* __restrict__ h2x,          // [bg][half][slot2][16][128] bf16
    int* __restrict__ cnt,                     // [layer][bg][half][wave]
    int ca, int TC, int NC)
{
  __shared__ unsigned short hbuf[2][16 * 256];   // full 16x256 h tile, double buffered
  const int tid = threadIdx.x;
  const int lane = tid & 63;
  const int w = tid >> 6;
  const int l15 = lane & 15, l4 = lane >> 4;
  const int bg = blockIdx.x & 7;
  const int layer = (blockIdx.x >> 3) & 1;
  const int half = (blockIdx.x >> 4) & 1;      // partner = blockIdx ^ 16 (co-XCD)
  const int chunk = layer ? ca - 1 : ca;
  if (layer ? (chunk < 0) : (chunk >= NC)) return;
  const int b0 = bg * 16;
  const int base = chunk * TC;
  const int unit = half * 128 + w * 16 + l15;
  char* lds = (char*)&hbuf[0][0];

  // register-resident W_hh half-slice: B-frag lane holds W[gt*256+unit][kk*32+8*l4 ..+8]
  const unsigned short* WA = layer ? whh1b : whh0b;
  short8 whh[4][8];
#pragma unroll
  for (int gt = 0; gt < 4; ++gt)
#pragma unroll
    for (int kk = 0; kk < 8; ++kk)
      whh[gt][kk] = *(const short8*)(WA + (size_t)(gt * 256 + unit) * 256 + kk * 32 + l4 * 8);

  float bs_l[4], wih0_l[4];
#pragma unroll
  for (int gt = 0; gt < 4; ++gt) {
    bs_l[gt] = (layer ? bsum1 : bsum0)[gt * 256 + unit];
    wih0_l[gt] = layer ? 0.0f : wih0[gt * 256 + unit];
  }

  float* hst = layer ? h2state : h1state;
  float* cst = layer ? c2state : c1state;

  float c_[4], psum[4], lasth[4];
  int len_[4];
#pragma unroll
  for (int r = 0; r < 4; ++r) {
    const int b = b0 + l4 * 4 + r;
    c_[r] = cst[(size_t)b * HH + unit];
    psum[r] = 0.f;
    lasth[r] = 0.f;
    len_[r] = lengths[b];
  }

  // initial full-h assembly into buf0 from carried state (both halves, no flags needed)
  for (int v = tid; v < 4096; v += 512) {
    const int s = v >> 8, u = v & 255;
    const int off = (s * 512 + u * 2) ^ ((s & 7) << 4);
    *(unsigned short*)(lds + off) = f2bf(hst[(size_t)(b0 + s) * HH + u]);
  }

  const int myci = ((layer * 8 + bg) * 2 + half) * 8 + w;
  const int pci  = ((layer * 8 + bg) * 2 + (half ^ 1)) * 8 + w;
  const int punit0 = (half ^ 1) * 128 + w * 16;   // wave w fills partner-wave-w's units
  const int fs = lane >> 2;                        // fill: sample
  const int fu = (lane & 3) * 4;                   // fill: unit offset (4 units = 8B)
  __syncthreads();

  for (int tl = 0; tl < TC; ++tl) {
    const int t = base + tl;
    const int p = tl & 1;
    char* ldsr = lds + p * 8192;
    char* ldsw = lds + (p ^ 1) * 8192;

    if (tl > 0) {
      // wait for partner wave w to have published h(t-1), then pull its 16 units
      while (__hip_atomic_load(&cnt[pci], __ATOMIC_ACQUIRE, __HIP_MEMORY_SCOPE_AGENT) < t)
        __builtin_amdgcn_s_sleep(2);
      uint2 d;
      if (!layer) {
        d = *(const uint2*)(h1buf + ((size_t)(b0 + fs) * TC + (tl - 1)) * 256 + punit0 + fu);
      } else {
        d = *(const uint2*)(h2x + ((((size_t)bg * 2 + (half ^ 1)) * 2 + ((t - 1) & 1)) * 16 + fs) * 128 + w * 16 + fu);
      }
      const int off = (fs * 512 + (punit0 + fu) * 2) ^ ((fs & 7) << 4);
      *(uint2*)(ldsr + off) = d;
    }
    __syncthreads();

    float xgv[4][4];
    if (layer) {
#pragma unroll
      for (int gt = 0; gt < 4; ++gt)
#pragma unroll
        for (int r = 0; r < 4; ++r)
          xgv[gt][r] = xg[((size_t)tl * BB + b0 + l4 * 4 + r) * 1024 + gt * 256 + unit];
    }

    short8 af[8];
#pragma unroll
    for (int kk = 0; kk < 8; ++kk) {
      const int off = (l15 * 512 + kk * 64 + l4 * 16) ^ ((l15 & 7) << 4);
      af[kk] = *(const short8*)(ldsr + off);
    }

    f32x4 z = {0.f, 0.f, 0.f, 0.f};
    f32x4 acc[4];
#pragma unroll
    for (int gt = 0; gt < 4; ++gt) acc[gt] = z;
#pragma unroll
    for (int gt = 0; gt < 4; ++gt)
#pragma unroll
      for (int kk = 0; kk < 8; ++kk)
        acc[gt] = __builtin_amdgcn_mfma_f32_16x16x32_bf16(af[kk], whh[gt][kk], acc[gt], 0, 0, 0);

#pragma unroll
    for (int r = 0; r < 4; ++r) {
      const int sr = l4 * 4 + r;
      const int b = b0 + sr;
      float pi = acc[0][r] + bs_l[0];
      float pf = acc[1][r] + bs_l[1];
      float pg = acc[2][r] + bs_l[2];
      float po = acc[3][r] + bs_l[3];
      if (!layer) {
        const float xv = x[(size_t)b * TT + t];
        pi += xv * wih0_l[0]; pf += xv * wih0_l[1];
        pg += xv * wih0_l[2]; po += xv * wih0_l[3];
      } else {
        pi += xgv[0][r]; pf += xgv[1][r];
        pg += xgv[2][r]; po += xgv[3][r];
      }
      const float ig = sigm(pi), fg = sigm(pf), gg = tanh_f(pg), og = sigm(po);
      const float cn = fg * c_[r] + ig * gg;
      c_[r] = cn;
      const float hn = og * tanh_f(cn);
      lasth[r] = hn;
      const unsigned short hb = f2bf(hn);
      const int off = (sr * 512 + unit * 2) ^ ((sr & 7) << 4);
      *(unsigned short*)(ldsw + off) = hb;
      if (!layer) {
        h1buf[((size_t)b * TC + tl) * 256 + unit] = hb;
      } else {
        h2x[((((size_t)bg * 2 + half) * 2 + (t & 1)) * 16 + sr) * 128 + (w * 16 + l15)] = hb;
        if (t < len_[r]) psum[r] += hn;
      }
    }
    // per-wave publish: drain this wave's stores, release counter
    if (lane == 0) {
      __threadfence();
      __hip_atomic_store(&cnt[myci], t + 1, __ATOMIC_RELEASE, __HIP_MEMORY_SCOPE_AGENT);
    }
  }

  // state writeback (h rounded to bf16 to match intra-chunk trajectory exactly)
#pragma unroll
  for (int r = 0; r < 4; ++r) {
    const int b = b0 + l4 * 4 + r;
    union { unsigned int u; float f; } v; v.u = ((unsigned int)f2bf(lasth[r])) << 16;
    hst[(size_t)b * HH + unit] = v.f;
    cst[(size_t)b * HH + unit] = c_[r];
    if (layer) pooled[(size_t)b * HH + unit] += psum[r];
  }
}

// ---------------- epilogue: masked-mean accumulated; apply 1/len and linear ------------------
__global__ void out_kernel(const float* __restrict__ pooled, const int* __restrict__ lengths,
                           const float* __restrict__ wlin, const float* __restrict__ blin,
                           float* __restrict__ out) {
  const int b = blockIdx.x;
  const int lane = threadIdx.x;   // 64
  float s[7];
#pragma unroll
  for (int c = 0; c < 7; ++c) s[c] = 0.f;
  for (int k = lane; k < 256; k += 64) {
    const float pv = pooled[b * 256 + k];
#pragma unroll
    for (int c = 0; c < 7; ++c) s[c] += pv * wlin[c * 256 + k];
  }
#pragma unroll
  for (int c = 0; c < 7; ++c) {
#pragma unroll
    for (int off = 32; off > 0; off >>= 1) s[c] += __shfl_down(s[c], off);
  }
  if (lane == 0) {
    const float inv = 1.0f / (float)lengths[b];
#pragma unroll
    for (int c = 0; c < 7; ++c) out[b * 7 + c] = s[c] * inv + blin[c];
  }
}

extern "C" void kernel_launch(void* const* d_in, const int* in_sizes, int n_in,
                              void* d_out, int out_size, void* d_ws, size_t ws_size,
                              hipStream_t stream) {
  const float* x      = (const float*)d_in[0];
  const int*   lengths= (const int*)d_in[1];
  const float* W_ih0  = (const float*)d_in[2];
  const float* W_hh0  = (const float*)d_in[3];
  const float* b_ih0  = (const float*)d_in[4];
  const float* b_hh0  = (const float*)d_in[5];
  const float* W_ih1  = (const float*)d_in[6];
  const float* W_hh1  = (const float*)d_in[7];
  const float* b_ih1  = (const float*)d_in[8];
  const float* b_hh1  = (const float*)d_in[9];
  const float* W_lin  = (const float*)d_in[10];
  const float* b_lin  = (const float*)d_in[11];
  float* out = (float*)d_out;

  char* ws = (char*)d_ws;
  unsigned short* whh0b = (unsigned short*)(ws + 0);
  unsigned short* wih1b = (unsigned short*)(ws + 524288);
  unsigned short* whh1b = (unsigned short*)(ws + 1048576);
  float* bsum0   = (float*)(ws + 1572864);
  float* bsum1   = (float*)(ws + 1576960);
  float* h1state = (float*)(ws + 1581056);   // start of zeroed span
  float* c1state = (float*)(ws + 1712128);
  float* h2state = (float*)(ws + 1843200);
  float* c2state = (float*)(ws + 1974272);
  float* pooled  = (float*)(ws + 2105344);
  int*   cnt     = (int*)  (ws + 2236416);   // 256 ints (zeroed by prep)
  unsigned short* h2x = (unsigned short*)(ws + 2237440);  // 128KB
  unsigned short* h1buf = (unsigned short*)(ws + 2368512);

  int TC = 128;
  while ((size_t)2368512 + 589824ull * TC > ws_size && TC > 16) TC >>= 1;
  const int NC = TT / TC;
  float* xg = (float*)(ws + 2368512 + 65536ull * TC);

  prep_kernel<<<dim3(1024), dim3(256), 0, stream>>>(
      W_hh0, W_ih1, W_hh1, b_ih0, b_hh0, b_ih1, b_hh1,
      whh0b, wih1b, whh1b, bsum0, bsum1, h1state);

  for (int ca = 0; ca <= NC; ++ca) {
    if (ca >= 1)
      xg_gemm<<<dim3(16 * (TC / 16)), dim3(512), 0, stream>>>(h1buf, wih1b, xg, TC);
    rec2<<<dim3(32), dim3(512), 0, stream>>>(
        x, whh0b, W_ih0, bsum0, whh1b, bsum1, xg, lengths,
        h1state, c1state, h2state, c2state, pooled, h1buf, h2x, cnt, ca, TC, NC);
  }

  out_kernel<<<dim3(128), dim3(64), 0, stream>>>(pooled, lengths, W_lin, b_lin, out);
}

// Round 3
// 26472.473 us; speedup vs baseline: 2.3207x; 1.2152x over previous
//
#include <hip/hip_runtime.h>
#include <stdint.h>

#define TT 2048
#define HH 256
#define BB 128

typedef __attribute__((ext_vector_type(8))) short short8;   // 8 x bf16 (4 VGPRs)
typedef __attribute__((ext_vector_type(4))) float f32x4;    // 4 x f32 acc

__device__ __forceinline__ unsigned short f2bf(float f) {
  union { float f; unsigned int u; } v; v.f = f;
  unsigned int r = v.u + 0x7fffu + ((v.u >> 16) & 1u);   // RNE
  return (unsigned short)(r >> 16);
}
__device__ __forceinline__ float sigm(float x) { return 1.0f / (1.0f + __expf(-x)); }
__device__ __forceinline__ float tanh_f(float x) { return 1.0f - 2.0f / (1.0f + __expf(2.0f * x)); }

// ---------------- prep: weight bf16 conversion, bias sums, zero flags ----------------
__global__ void prep_kernel(const float* __restrict__ whh0, const float* __restrict__ wih1,
                            const float* __restrict__ whh1,
                            const float* __restrict__ bih0, const float* __restrict__ bhh0,
                            const float* __restrict__ bih1, const float* __restrict__ bhh1,
                            unsigned short* __restrict__ whh0b, unsigned short* __restrict__ wih1b,
                            unsigned short* __restrict__ whh1b,
                            float* __restrict__ bsum0, float* __restrict__ bsum1,
                            int* __restrict__ flags) {
  int i = blockIdx.x * blockDim.x + threadIdx.x;   // 262144 threads exactly
  if (i < 262144) {
    whh0b[i] = f2bf(whh0[i]);
    wih1b[i] = f2bf(wih1[i]);
    whh1b[i] = f2bf(whh1[i]);
  }
  if (i < 1024) bsum0[i] = bih0[i] + bhh0[i];
  else if (i < 2048) { int j = i - 1024; bsum1[j] = bih1[j] + bhh1[j]; }
  if (i < 512) flags[i] = 0;
}

// single-flag wait (all lanes same idx)
__device__ __forceinline__ void wait1(int* f, int idx, int target) {
  while (__hip_atomic_load(&f[idx], __ATOMIC_RELAXED, __HIP_MEMORY_SCOPE_AGENT) < target)
    __builtin_amdgcn_s_sleep(1);
  __builtin_amdgcn_fence(__ATOMIC_ACQUIRE, "agent");
}
// multi-flag wait (per-lane idx, wave-collective)
__device__ __forceinline__ void waitN(int* f, int idx, int target) {
  for (;;) {
    int v = __hip_atomic_load(&f[idx], __ATOMIC_RELAXED, __HIP_MEMORY_SCOPE_AGENT);
    if (__all(v >= target)) break;
    __builtin_amdgcn_s_sleep(1);
  }
  __builtin_amdgcn_fence(__ATOMIC_ACQUIRE, "agent");
}

// ---------------- fused 3-stage pipeline over all T in ONE launch ----------------
// blocks 0-15: L0 (wgid = half*8+bg), 16-31: XG (uh*8+bg), 32-47: L1 (half*8+bg).
// Weights register-resident (128 VGPR/lane). Flags: [stage][wgid][wave] step counters.
__attribute__((amdgpu_flat_work_group_size(512, 512)))
__attribute__((amdgpu_waves_per_eu(2, 2)))
__global__ void rec_all(
    const float* __restrict__ x,
    const unsigned short* __restrict__ whh0b, const float* __restrict__ wih0,
    const float* __restrict__ bsum0,
    const unsigned short* __restrict__ wih1b,
    const unsigned short* __restrict__ whh1b, const float* __restrict__ bsum1,
    const int* __restrict__ lengths,
    float* __restrict__ pooled,
    unsigned short* __restrict__ h1ring,   // [8][128][256] bf16
    float* __restrict__ xgring,            // [8][8bg][2uh][16][512] f32
    unsigned short* __restrict__ h2x,      // [2][8bg][2half][16][128] bf16
    int* flags)
{
  __shared__ unsigned short hbuf[2][16 * 256];   // 16KB double-buffered h tile
  const int tid = threadIdx.x;
  const int lane = tid & 63;
  const int w = tid >> 6;
  const int l15 = lane & 15, l4 = lane >> 4;
  const int stage = blockIdx.x >> 4;
  const int wgid = blockIdx.x & 15;
  const int half = wgid >> 3;              // uh for stage 1
  const int bg = wgid & 7;
  const int b0 = bg * 16;
  const int myf = stage * 128 + wgid * 8 + w;
  char* lds = (char*)&hbuf[0][0];
  const int fs = lane >> 2;                // exchange fill: sample
  const int fu = (lane & 3) * 4;           // exchange fill: unit offset (4 units = 8B)
  const int punit0 = (half ^ 1) * 128 + w * 16;
  const int g16 = (lane >> 3) & 1;         // 16-flag wait: group select

  if (stage == 0) {
    // ---------------- L0: h1 recurrence ----------------
    const int unit = half * 128 + w * 16 + l15;
    short8 wf[4][8];
#pragma unroll
    for (int gt = 0; gt < 4; ++gt)
#pragma unroll
      for (int kk = 0; kk < 8; ++kk)
        wf[gt][kk] = *(const short8*)(whh0b + (size_t)(gt * 256 + unit) * 256 + kk * 32 + l4 * 8);
    float bs_l[4], wih0_l[4];
#pragma unroll
    for (int gt = 0; gt < 4; ++gt) { bs_l[gt] = bsum0[gt * 256 + unit]; wih0_l[gt] = wih0[gt * 256 + unit]; }

    for (int v = tid; v < 4096; v += 512) ((unsigned int*)lds)[v] = 0;
    __syncthreads();

    float c_[4] = {0.f, 0.f, 0.f, 0.f};
    for (int t = 0; t < TT; ++t) {
      const int p = t & 1;
      char* ldsr = lds + p * 8192;
      char* ldsw = lds + (p ^ 1) * 8192;
      if (t > 0) {
        wait1(flags, 0 * 128 + (wgid ^ 8) * 8 + w, t);
        uint2 d = *(const uint2*)(h1ring + ((size_t)((t - 1) & 7) * BB + b0 + fs) * HH + punit0 + fu);
        *(uint2*)(ldsr + ((fs * 512 + (punit0 + fu) * 2) ^ ((fs & 7) << 4))) = d;
      }
      if (t >= 8) waitN(flags, 128 + g16 * 64 + bg * 8 + (lane & 7), t - 7);   // XG credit
      __syncthreads();

      float xv[4];
#pragma unroll
      for (int r = 0; r < 4; ++r) xv[r] = x[(size_t)(b0 + l4 * 4 + r) * TT + t];

      short8 af[8];
#pragma unroll
      for (int kk = 0; kk < 8; ++kk)
        af[kk] = *(const short8*)(ldsr + ((l15 * 512 + kk * 64 + l4 * 16) ^ ((l15 & 7) << 4)));

      f32x4 z = {0.f, 0.f, 0.f, 0.f};
      f32x4 acc[4];
#pragma unroll
      for (int gt = 0; gt < 4; ++gt) acc[gt] = z;
#pragma unroll
      for (int gt = 0; gt < 4; ++gt)
#pragma unroll
        for (int kk = 0; kk < 8; ++kk)
          acc[gt] = __builtin_amdgcn_mfma_f32_16x16x32_bf16(af[kk], wf[gt][kk], acc[gt], 0, 0, 0);

#pragma unroll
      for (int r = 0; r < 4; ++r) {
        const int sr = l4 * 4 + r;
        float pi = acc[0][r] + bs_l[0] + xv[r] * wih0_l[0];
        float pf = acc[1][r] + bs_l[1] + xv[r] * wih0_l[1];
        float pg = acc[2][r] + bs_l[2] + xv[r] * wih0_l[2];
        float po = acc[3][r] + bs_l[3] + xv[r] * wih0_l[3];
        const float ig = sigm(pi), fg = sigm(pf), gg = tanh_f(pg), og = sigm(po);
        const float cn = fg * c_[r] + ig * gg;
        c_[r] = cn;
        const float hn = og * tanh_f(cn);
        const unsigned short hb = f2bf(hn);
        h1ring[((size_t)(t & 7) * BB + b0 + sr) * HH + unit] = hb;
        *(unsigned short*)(ldsw + ((sr * 512 + unit * 2) ^ ((sr & 7) << 4))) = hb;
      }
      if (lane == 0)
        __hip_atomic_store(&flags[myf], t + 1, __ATOMIC_RELEASE, __HIP_MEMORY_SCOPE_AGENT);
    }
  } else if (stage == 1) {
    // ---------------- XG: xg(t) = W_ih1 . h1(t) ----------------
    short8 wf[4][8];
#pragma unroll
    for (int nt = 0; nt < 4; ++nt)
#pragma unroll
      for (int kk = 0; kk < 8; ++kk) {
        const int r512 = (w * 4 + nt) * 16 + l15;
        const int row = (r512 >> 7) * 256 + half * 128 + (r512 & 127);
        wf[nt][kk] = *(const short8*)(wih1b + (size_t)row * 256 + kk * 32 + l4 * 8);
      }

    for (int t = 0; t < TT; ++t) {
      waitN(flags, 0 + g16 * 64 + bg * 8 + (lane & 7), t + 1);                 // h1(t) ready
      if (t >= 8) waitN(flags, 256 + half * 64 + bg * 8 + (lane & 7), t - 7);  // L1 credit

      short8 af[8];
#pragma unroll
      for (int kk = 0; kk < 8; ++kk)
        af[kk] = *(const short8*)(h1ring + ((size_t)(t & 7) * BB + b0 + l15) * HH + kk * 32 + l4 * 8);

      f32x4 z = {0.f, 0.f, 0.f, 0.f};
      f32x4 acc[4];
#pragma unroll
      for (int nt = 0; nt < 4; ++nt) acc[nt] = z;
#pragma unroll
      for (int nt = 0; nt < 4; ++nt)
#pragma unroll
        for (int kk = 0; kk < 8; ++kk)
          acc[nt] = __builtin_amdgcn_mfma_f32_16x16x32_bf16(af[kk], wf[nt][kk], acc[nt], 0, 0, 0);

      const size_t xb = (((size_t)(t & 7) * 8 + bg) * 2 + half) * 8192;
#pragma unroll
      for (int nt = 0; nt < 4; ++nt)
#pragma unroll
        for (int r = 0; r < 4; ++r)
          xgring[xb + (size_t)(l4 * 4 + r) * 512 + (w * 4 + nt) * 16 + l15] = acc[nt][r];

      if (lane == 0)
        __hip_atomic_store(&flags[myf], t + 1, __ATOMIC_RELEASE, __HIP_MEMORY_SCOPE_AGENT);
    }
  } else {
    // ---------------- L1: h2 recurrence + masked pooling ----------------
    const int unit = half * 128 + w * 16 + l15;
    short8 wf[4][8];
#pragma unroll
    for (int gt = 0; gt < 4; ++gt)
#pragma unroll
      for (int kk = 0; kk < 8; ++kk)
        wf[gt][kk] = *(const short8*)(whh1b + (size_t)(gt * 256 + unit) * 256 + kk * 32 + l4 * 8);
    float bs_l[4];
#pragma unroll
    for (int gt = 0; gt < 4; ++gt) bs_l[gt] = bsum1[gt * 256 + unit];

    for (int v = tid; v < 4096; v += 512) ((unsigned int*)lds)[v] = 0;
    __syncthreads();

    float c_[4] = {0.f, 0.f, 0.f, 0.f};
    float psum[4] = {0.f, 0.f, 0.f, 0.f};
    int len_[4];
#pragma unroll
    for (int r = 0; r < 4; ++r) len_[r] = lengths[b0 + l4 * 4 + r];

    for (int t = 0; t < TT; ++t) {
      const int p = t & 1;
      char* ldsr = lds + p * 8192;
      char* ldsw = lds + (p ^ 1) * 8192;
      waitN(flags, 128 + half * 64 + bg * 8 + (lane & 7), t + 1);              // xg(t) ready
      if (t > 0) {
        wait1(flags, 256 + (wgid ^ 8) * 8 + w, t);
        uint2 d = *(const uint2*)(h2x + ((((size_t)((t - 1) & 1) * 8 + bg) * 2 + (half ^ 1)) * 16 + fs) * 128 + w * 16 + fu);
        *(uint2*)(ldsr + ((fs * 512 + (punit0 + fu) * 2) ^ ((fs & 7) << 4))) = d;
      }
      __syncthreads();

      const size_t xb = (((size_t)(t & 7) * 8 + bg) * 2 + half) * 8192;
      float xgv[4][4];
#pragma unroll
      for (int gt = 0; gt < 4; ++gt)
#pragma unroll
        for (int r = 0; r < 4; ++r)
          xgv[gt][r] = xgring[xb + (size_t)(l4 * 4 + r) * 512 + gt * 128 + w * 16 + l15];

      short8 af[8];
#pragma unroll
      for (int kk = 0; kk < 8; ++kk)
        af[kk] = *(const short8*)(ldsr + ((l15 * 512 + kk * 64 + l4 * 16) ^ ((l15 & 7) << 4)));

      f32x4 z = {0.f, 0.f, 0.f, 0.f};
      f32x4 acc[4];
#pragma unroll
      for (int gt = 0; gt < 4; ++gt) acc[gt] = z;
#pragma unroll
      for (int gt = 0; gt < 4; ++gt)
#pragma unroll
        for (int kk = 0; kk < 8; ++kk)
          acc[gt] = __builtin_amdgcn_mfma_f32_16x16x32_bf16(af[kk], wf[gt][kk], acc[gt], 0, 0, 0);

#pragma unroll
      for (int r = 0; r < 4; ++r) {
        const int sr = l4 * 4 + r;
        float pi = acc[0][r] + bs_l[0] + xgv[0][r];
        float pf = acc[1][r] + bs_l[1] + xgv[1][r];
        float pg = acc[2][r] + bs_l[2] + xgv[2][r];
        float po = acc[3][r] + bs_l[3] + xgv[3][r];
        const float ig = sigm(pi), fg = sigm(pf), gg = tanh_f(pg), og = sigm(po);
        const float cn = fg * c_[r] + ig * gg;
        c_[r] = cn;
        const float hn = og * tanh_f(cn);
        const unsigned short hb = f2bf(hn);
        h2x[((((size_t)(t & 1) * 8 + bg) * 2 + half) * 16 + sr) * 128 + w * 16 + l15] = hb;
        *(unsigned short*)(ldsw + ((sr * 512 + unit * 2) ^ ((sr & 7) << 4))) = hb;
        if (t < len_[r]) psum[r] += hn;
      }
      if (lane == 0)
        __hip_atomic_store(&flags[myf], t + 1, __ATOMIC_RELEASE, __HIP_MEMORY_SCOPE_AGENT);
    }
#pragma unroll
    for (int r = 0; r < 4; ++r)
      pooled[(size_t)(b0 + l4 * 4 + r) * HH + unit] = psum[r];
  }
}

// ---------------- epilogue: apply 1/len and linear head ----------------
__global__ void out_kernel(const float* __restrict__ pooled, const int* __restrict__ lengths,
                           const float* __restrict__ wlin, const float* __restrict__ blin,
                           float* __restrict__ out) {
  const int b = blockIdx.x;
  const int lane = threadIdx.x;   // 64
  float s[7];
#pragma unroll
  for (int c = 0; c < 7; ++c) s[c] = 0.f;
  for (int k = lane; k < 256; k += 64) {
    const float pv = pooled[b * 256 + k];
#pragma unroll
    for (int c = 0; c < 7; ++c) s[c] += pv * wlin[c * 256 + k];
  }
#pragma unroll
  for (int c = 0; c < 7; ++c) {
#pragma unroll
    for (int off = 32; off > 0; off >>= 1) s[c] += __shfl_down(s[c], off);
  }
  if (lane == 0) {
    const float inv = 1.0f / (float)lengths[b];
#pragma unroll
    for (int c = 0; c < 7; ++c) out[b * 7 + c] = s[c] * inv + blin[c];
  }
}

extern "C" void kernel_launch(void* const* d_in, const int* in_sizes, int n_in,
                              void* d_out, int out_size, void* d_ws, size_t ws_size,
                              hipStream_t stream) {
  const float* x      = (const float*)d_in[0];
  const int*   lengths= (const int*)d_in[1];
  const float* W_ih0  = (const float*)d_in[2];
  const float* W_hh0  = (const float*)d_in[3];
  const float* b_ih0  = (const float*)d_in[4];
  const float* b_hh0  = (const float*)d_in[5];
  const float* W_ih1  = (const float*)d_in[6];
  const float* W_hh1  = (const float*)d_in[7];
  const float* b_ih1  = (const float*)d_in[8];
  const float* b_hh1  = (const float*)d_in[9];
  const float* W_lin  = (const float*)d_in[10];
  const float* b_lin  = (const float*)d_in[11];
  float* out = (float*)d_out;

  char* ws = (char*)d_ws;
  unsigned short* whh0b = (unsigned short*)(ws + 0);
  unsigned short* wih1b = (unsigned short*)(ws + 524288);
  unsigned short* whh1b = (unsigned short*)(ws + 1048576);
  float* bsum0   = (float*)(ws + 1572864);
  float* bsum1   = (float*)(ws + 1576960);
  int*   flags   = (int*)  (ws + 1581056);            // 512 ints
  float* pooled  = (float*)(ws + 1583104);            // 128KB
  unsigned short* h2x    = (unsigned short*)(ws + 1714176);   // 128KB
  unsigned short* h1ring = (unsigned short*)(ws + 1845248);   // 512KB
  float* xgring  = (float*)(ws + 2369536);            // 4MB

  prep_kernel<<<dim3(1024), dim3(256), 0, stream>>>(
      W_hh0, W_ih1, W_hh1, b_ih0, b_hh0, b_ih1, b_hh1,
      whh0b, wih1b, whh1b, bsum0, bsum1, flags);

  rec_all<<<dim3(48), dim3(512), 0, stream>>>(
      x, whh0b, W_ih0, bsum0, wih1b, whh1b, bsum1, lengths,
      pooled, h1ring, xgring, h2x, flags);

  out_kernel<<<dim3(128), dim3(64), 0, stream>>>(pooled, lengths, W_lin, b_lin, out);
}

// Round 4
// 14962.903 us; speedup vs baseline: 4.1058x; 1.7692x over previous
//
#include <hip/hip_runtime.h>
#include <stdint.h>

#define TT 2048
#define HH 256
#define BB 128

typedef __attribute__((ext_vector_type(8))) short short8;   // 8 x bf16 (4 VGPRs)
typedef __attribute__((ext_vector_type(4))) float f32x4;    // 4 x f32 acc

__device__ __forceinline__ unsigned short f2bf(float f) {
  union { float f; unsigned int u; } v; v.f = f;
  unsigned int r = v.u + 0x7fffu + ((v.u >> 16) & 1u);   // RNE
  return (unsigned short)(r >> 16);
}
__device__ __forceinline__ float sigm(float x) { return 1.0f / (1.0f + __expf(-x)); }
__device__ __forceinline__ float tanh_f(float x) { return 1.0f - 2.0f / (1.0f + __expf(2.0f * x)); }

// MFMA with B operand pinned to AGPRs ("a" constraint) -> weights stay register-resident.
__device__ __forceinline__ void mfma_bf16(f32x4& acc, short8 a, short8 b) {
  asm("v_mfma_f32_16x16x32_bf16 %0, %1, %2, %0" : "+v"(acc) : "v"(a), "a"(b));
}
// coherent (IC-level) accesses: per-instruction scope bits, NO cache-wide fences
__device__ __forceinline__ short8 ld16_ic(const unsigned short* p) {
  union { unsigned long long q[2]; short8 v; } u;
  u.q[0] = __hip_atomic_load((const unsigned long long*)p, __ATOMIC_RELAXED, __HIP_MEMORY_SCOPE_AGENT);
  u.q[1] = __hip_atomic_load(((const unsigned long long*)p) + 1, __ATOMIC_RELAXED, __HIP_MEMORY_SCOPE_AGENT);
  return u.v;
}
__device__ __forceinline__ float ld4f_ic(const float* p) {
  union { unsigned int u; float f; } c;
  c.u = __hip_atomic_load((const unsigned int*)p, __ATOMIC_RELAXED, __HIP_MEMORY_SCOPE_AGENT);
  return c.f;
}
__device__ __forceinline__ void st2_ic(unsigned short* p, unsigned short v) {
  unsigned int vv = v;
  asm volatile("global_store_short %0, %1, off sc0 sc1" :: "v"(p), "v"(vv) : "memory");
}
__device__ __forceinline__ void st4f_ic(float* p, float v) {
  union { float f; unsigned int u; } c; c.f = v;
  __hip_atomic_store((unsigned int*)p, c.u, __ATOMIC_RELAXED, __HIP_MEMORY_SCOPE_AGENT);
}
__device__ __forceinline__ void vmcnt0() { asm volatile("s_waitcnt vmcnt(0)" ::: "memory"); }
// wave-collective poll over per-lane (flag index, target); flags padded x16 ints
__device__ __forceinline__ void waitN(int* f, int idx, int tgt) {
  for (;;) {
    int v = __hip_atomic_load(&f[idx * 16], __ATOMIC_RELAXED, __HIP_MEMORY_SCOPE_AGENT);
    if (__all(v >= tgt)) break;
    __builtin_amdgcn_s_sleep(2);
  }
}

// ---------------- prep: weight bf16 conversion, bias sums, zero flags ----------------
__global__ void prep_kernel(const float* __restrict__ whh0, const float* __restrict__ wih1,
                            const float* __restrict__ whh1,
                            const float* __restrict__ bih0, const float* __restrict__ bhh0,
                            const float* __restrict__ bih1, const float* __restrict__ bhh1,
                            unsigned short* __restrict__ whh0b, unsigned short* __restrict__ wih1b,
                            unsigned short* __restrict__ whh1b,
                            float* __restrict__ bsum0, float* __restrict__ bsum1,
                            int* __restrict__ flags) {
  int i = blockIdx.x * blockDim.x + threadIdx.x;   // 262144 threads exactly
  if (i < 262144) {
    whh0b[i] = f2bf(whh0[i]);
    wih1b[i] = f2bf(wih1[i]);
    whh1b[i] = f2bf(whh1[i]);
  }
  if (i < 1024) bsum0[i] = bih0[i] + bhh0[i];
  else if (i < 2048) { int j = i - 1024; bsum1[j] = bih1[j] + bhh1[j]; }
  if (i < 8192) flags[i] = 0;
}

// ---------------- fused 3-stage pipeline, one launch, no LDS, no fences ----------------
// blocks 0-15: L0 (half*8+bg), 16-31: XG (uh*8+bg), 32-47: L1 (half*8+bg).
// flags flat index = stage*128 + wg16*8 + wave (each padded to 64B).
__attribute__((amdgpu_flat_work_group_size(512, 512)))
__attribute__((amdgpu_waves_per_eu(2, 2)))
__global__ void rec_all(
    const float* __restrict__ x,
    const unsigned short* __restrict__ whh0b, const float* __restrict__ wih0,
    const float* __restrict__ bsum0,
    const unsigned short* __restrict__ wih1b,
    const unsigned short* __restrict__ whh1b, const float* __restrict__ bsum1,
    const int* __restrict__ lengths,
    float* __restrict__ pooled,
    unsigned short* __restrict__ h1ring,   // [8][128][256] bf16
    float* __restrict__ xgring,            // [8][128][1024] f32
    unsigned short* __restrict__ h2ring,   // [2][128][256] bf16
    int* flags)
{
  const int tid = threadIdx.x;
  const int lane = tid & 63;
  const int w = tid >> 6;
  const int l15 = lane & 15, l4 = lane >> 4;
  const int stage = blockIdx.x >> 4;
  const int wg16 = blockIdx.x & 15;
  const int half = wg16 >> 3;
  const int bg = wg16 & 7;
  const int b0 = bg * 16;
  const int myflat = stage * 128 + wg16 * 8 + w;

  if (stage == 0) {
    // ================= L0: h1 recurrence =================
    const int unit = half * 128 + w * 16 + l15;
    short8 wf[4][8];
#pragma unroll
    for (int gt = 0; gt < 4; ++gt)
#pragma unroll
      for (int kk = 0; kk < 8; ++kk)
        wf[gt][kk] = *(const short8*)(whh0b + (size_t)(gt * 256 + unit) * 256 + kk * 32 + l4 * 8);
    float bs_l[4], wih0_l[4];
#pragma unroll
    for (int gt = 0; gt < 4; ++gt) { bs_l[gt] = bsum0[gt * 256 + unit]; wih0_l[gt] = wih0[gt * 256 + unit]; }

    float c_[4] = {0.f, 0.f, 0.f, 0.f};
    for (int t = 0; t < TT; ++t) {
      if (t > 0) {
        int idx = 0, tgt = 0;
        if (lane < 8) { idx = ((half ^ 1) * 8 + bg) * 8 + lane; tgt = t; }                       // partner h1(t-1)
        else if (lane >= 16 && lane < 32) {                                                      // XG ring credit
          idx = 128 + (((lane >> 3) & 1) * 8 + bg) * 8 + (lane & 7);
          tgt = ((t & 7) == 0 && t >= 8) ? t : 0;
        }
        waitN(flags, idx, tgt);
      }

      f32x4 acc[4];
      f32x4 z = {0.f, 0.f, 0.f, 0.f};
#pragma unroll
      for (int gt = 0; gt < 4; ++gt) acc[gt] = z;
      if (t > 0) {
        const unsigned short* hrow = h1ring + ((size_t)((t - 1) & 7) * BB + b0 + l15) * HH;
        short8 af[8];
#pragma unroll
        for (int kk = 0; kk < 8; ++kk) af[kk] = ld16_ic(hrow + kk * 32 + l4 * 8);
#pragma unroll
        for (int gt = 0; gt < 4; ++gt)
#pragma unroll
          for (int kk = 0; kk < 8; ++kk) mfma_bf16(acc[gt], af[kk], wf[gt][kk]);
      }

#pragma unroll
      for (int r = 0; r < 4; ++r) {
        const int sr = l4 * 4 + r;
        const float xv = x[(size_t)(b0 + sr) * TT + t];
        float pi = acc[0][r] + bs_l[0] + xv * wih0_l[0];
        float pf = acc[1][r] + bs_l[1] + xv * wih0_l[1];
        float pg = acc[2][r] + bs_l[2] + xv * wih0_l[2];
        float po = acc[3][r] + bs_l[3] + xv * wih0_l[3];
        const float ig = sigm(pi), fg = sigm(pf), gg = tanh_f(pg), og = sigm(po);
        const float cn = fg * c_[r] + ig * gg;
        c_[r] = cn;
        const float hn = og * tanh_f(cn);
        st2_ic(&h1ring[((size_t)(t & 7) * BB + b0 + sr) * HH + unit], f2bf(hn));
      }
      vmcnt0();
      if (lane == 0)
        __hip_atomic_store(&flags[myflat * 16], t + 1, __ATOMIC_RELAXED, __HIP_MEMORY_SCOPE_AGENT);
      __syncthreads();   // own-WG lockstep: all stores of step t at IC before t+1 reads
    }
  } else if (stage == 1) {
    // ================= XG: xg(t) = W_ih1 . h1(t) =================
    const int uh = half;
    short8 wf[4][8];
    int gidx[4];
#pragma unroll
    for (int nt = 0; nt < 4; ++nt) {
      const int r512 = (w * 4 + nt) * 16 + l15;
      const int g = (r512 >> 7) * 256 + uh * 128 + (r512 & 127);
      gidx[nt] = g;
#pragma unroll
      for (int kk = 0; kk < 8; ++kk)
        wf[nt][kk] = *(const short8*)(wih1b + (size_t)g * 256 + kk * 32 + l4 * 8);
    }

    for (int t = 0; t < TT; ++t) {
      {
        int idx = 0, tgt = 0;
        if (lane < 16) { idx = ((lane >> 3) * 8 + bg) * 8 + (lane & 7); tgt = t + 1; }          // h1(t) ready
        else if (lane < 32) {                                                                   // L1 ring credit
          idx = 256 + (((lane >> 3) & 1) * 8 + bg) * 8 + (lane & 7);
          tgt = ((t & 7) == 0 && t >= 8) ? t : 0;
        }
        waitN(flags, idx, tgt);
      }

      const unsigned short* hrow = h1ring + ((size_t)(t & 7) * BB + b0 + l15) * HH;
      short8 af[8];
#pragma unroll
      for (int kk = 0; kk < 8; ++kk) af[kk] = ld16_ic(hrow + kk * 32 + l4 * 8);

      f32x4 acc[4];
      f32x4 z = {0.f, 0.f, 0.f, 0.f};
#pragma unroll
      for (int nt = 0; nt < 4; ++nt) acc[nt] = z;
#pragma unroll
      for (int nt = 0; nt < 4; ++nt)
#pragma unroll
        for (int kk = 0; kk < 8; ++kk) mfma_bf16(acc[nt], af[kk], wf[nt][kk]);

#pragma unroll
      for (int nt = 0; nt < 4; ++nt)
#pragma unroll
        for (int r = 0; r < 4; ++r)
          st4f_ic(&xgring[((size_t)(t & 7) * BB + b0 + l4 * 4 + r) * 1024 + gidx[nt]], acc[nt][r]);

      vmcnt0();
      if (lane == 0)
        __hip_atomic_store(&flags[myflat * 16], t + 1, __ATOMIC_RELAXED, __HIP_MEMORY_SCOPE_AGENT);
    }
  } else {
    // ================= L1: h2 recurrence + masked pooling =================
    const int unit = half * 128 + w * 16 + l15;
    short8 wf[4][8];
#pragma unroll
    for (int gt = 0; gt < 4; ++gt)
#pragma unroll
      for (int kk = 0; kk < 8; ++kk)
        wf[gt][kk] = *(const short8*)(whh1b + (size_t)(gt * 256 + unit) * 256 + kk * 32 + l4 * 8);
    float bs_l[4];
#pragma unroll
    for (int gt = 0; gt < 4; ++gt) bs_l[gt] = bsum1[gt * 256 + unit];

    float c_[4] = {0.f, 0.f, 0.f, 0.f};
    float psum[4] = {0.f, 0.f, 0.f, 0.f};
    int len_[4];
#pragma unroll
    for (int r = 0; r < 4; ++r) len_[r] = lengths[b0 + l4 * 4 + r];

    for (int t = 0; t < TT; ++t) {
      {
        int idx = 0, tgt = 0;
        if (lane < 8) { idx = 128 + (half * 8 + bg) * 8 + lane; tgt = t + 1; }                  // xg(t) ready
        else if (lane < 16) { idx = 256 + ((half ^ 1) * 8 + bg) * 8 + (lane & 7); tgt = (t > 0) ? t : 0; } // partner h2(t-1)
        waitN(flags, idx, tgt);
      }

      float xgv[4][4];
#pragma unroll
      for (int gt = 0; gt < 4; ++gt)
#pragma unroll
        for (int r = 0; r < 4; ++r)
          xgv[gt][r] = ld4f_ic(&xgring[((size_t)(t & 7) * BB + b0 + l4 * 4 + r) * 1024 + gt * 256 + half * 128 + w * 16 + l15]);

      f32x4 acc[4];
      f32x4 z = {0.f, 0.f, 0.f, 0.f};
#pragma unroll
      for (int gt = 0; gt < 4; ++gt) acc[gt] = z;
      if (t > 0) {
        const unsigned short* hrow = h2ring + ((size_t)((t - 1) & 1) * BB + b0 + l15) * HH;
        short8 af[8];
#pragma unroll
        for (int kk = 0; kk < 8; ++kk) af[kk] = ld16_ic(hrow + kk * 32 + l4 * 8);
#pragma unroll
        for (int gt = 0; gt < 4; ++gt)
#pragma unroll
          for (int kk = 0; kk < 8; ++kk) mfma_bf16(acc[gt], af[kk], wf[gt][kk]);
      }

#pragma unroll
      for (int r = 0; r < 4; ++r) {
        const int sr = l4 * 4 + r;
        float pi = acc[0][r] + bs_l[0] + xgv[0][r];
        float pf = acc[1][r] + bs_l[1] + xgv[1][r];
        float pg = acc[2][r] + bs_l[2] + xgv[2][r];
        float po = acc[3][r] + bs_l[3] + xgv[3][r];
        const float ig = sigm(pi), fg = sigm(pf), gg = tanh_f(pg), og = sigm(po);
        const float cn = fg * c_[r] + ig * gg;
        c_[r] = cn;
        const float hn = og * tanh_f(cn);
        st2_ic(&h2ring[((size_t)(t & 1) * BB + b0 + sr) * HH + unit], f2bf(hn));
        if (t < len_[r]) psum[r] += hn;
      }
      vmcnt0();
      if (lane == 0)
        __hip_atomic_store(&flags[myflat * 16], t + 1, __ATOMIC_RELAXED, __HIP_MEMORY_SCOPE_AGENT);
      __syncthreads();
    }
#pragma unroll
    for (int r = 0; r < 4; ++r)
      pooled[(size_t)(b0 + l4 * 4 + r) * HH + unit] = psum[r];
  }
}

// ---------------- epilogue: apply 1/len and linear head ----------------
__global__ void out_kernel(const float* __restrict__ pooled, const int* __restrict__ lengths,
                           const float* __restrict__ wlin, const float* __restrict__ blin,
                           float* __restrict__ out) {
  const int b = blockIdx.x;
  const int lane = threadIdx.x;   // 64
  float s[7];
#pragma unroll
  for (int c = 0; c < 7; ++c) s[c] = 0.f;
  for (int k = lane; k < 256; k += 64) {
    const float pv = pooled[b * 256 + k];
#pragma unroll
    for (int c = 0; c < 7; ++c) s[c] += pv * wlin[c * 256 + k];
  }
#pragma unroll
  for (int c = 0; c < 7; ++c) {
#pragma unroll
    for (int off = 32; off > 0; off >>= 1) s[c] += __shfl_down(s[c], off);
  }
  if (lane == 0) {
    const float inv = 1.0f / (float)lengths[b];
#pragma unroll
    for (int c = 0; c < 7; ++c) out[b * 7 + c] = s[c] * inv + blin[c];
  }
}

extern "C" void kernel_launch(void* const* d_in, const int* in_sizes, int n_in,
                              void* d_out, int out_size, void* d_ws, size_t ws_size,
                              hipStream_t stream) {
  const float* x      = (const float*)d_in[0];
  const int*   lengths= (const int*)d_in[1];
  const float* W_ih0  = (const float*)d_in[2];
  const float* W_hh0  = (const float*)d_in[3];
  const float* b_ih0  = (const float*)d_in[4];
  const float* b_hh0  = (const float*)d_in[5];
  const float* W_ih1  = (const float*)d_in[6];
  const float* W_hh1  = (const float*)d_in[7];
  const float* b_ih1  = (const float*)d_in[8];
  const float* b_hh1  = (const float*)d_in[9];
  const float* W_lin  = (const float*)d_in[10];
  const float* b_lin  = (const float*)d_in[11];
  float* out = (float*)d_out;

  char* ws = (char*)d_ws;
  unsigned short* whh0b = (unsigned short*)(ws + 0);
  unsigned short* wih1b = (unsigned short*)(ws + 524288);
  unsigned short* whh1b = (unsigned short*)(ws + 1048576);
  float* bsum0   = (float*)(ws + 1572864);
  float* bsum1   = (float*)(ws + 1576960);
  int*   flags   = (int*)  (ws + 1581056);                    // 8192 ints (padded flags)
  float* pooled  = (float*)(ws + 1613824);                    // 128KB
  unsigned short* h2ring = (unsigned short*)(ws + 1744896);   // 128KB
  unsigned short* h1ring = (unsigned short*)(ws + 1875968);   // 512KB
  float* xgring  = (float*)(ws + 2400256);                    // 4MB

  prep_kernel<<<dim3(1024), dim3(256), 0, stream>>>(
      W_hh0, W_ih1, W_hh1, b_ih0, b_hh0, b_ih1, b_hh1,
      whh0b, wih1b, whh1b, bsum0, bsum1, flags);

  rec_all<<<dim3(48), dim3(512), 0, stream>>>(
      x, whh0b, W_ih0, bsum0, wih1b, whh1b, bsum1, lengths,
      pooled, h1ring, xgring, h2ring, flags);

  out_kernel<<<dim3(128), dim3(64), 0, stream>>>(pooled, lengths, W_lin, b_lin, out);
}

// Round 9
// 12605.154 us; speedup vs baseline: 4.8738x; 1.1870x over previous
//
#include <hip/hip_runtime.h>
#include <stdint.h>

#define TT 2048
#define HH 256
#define BB 128

typedef __attribute__((ext_vector_type(8))) short short8;   // 8 x bf16 (4 VGPRs)
typedef __attribute__((ext_vector_type(4))) float f32x4;    // 4 x f32 acc

__device__ __forceinline__ unsigned short f2bf(float f) {
  union { float f; unsigned int u; } v; v.f = f;
  unsigned int r = v.u + 0x7fffu + ((v.u >> 16) & 1u);   // RNE
  return (unsigned short)(r >> 16);
}
__device__ __forceinline__ float sigm(float x) { return 1.0f / (1.0f + __expf(-x)); }
__device__ __forceinline__ float tanh_f(float x) { return 1.0f - 2.0f / (1.0f + __expf(2.0f * x)); }

// MFMA, B pinned to AGPR (weights resident) / B in VGPR (second weight set)
__device__ __forceinline__ void mfma_a(f32x4& acc, short8 a, short8 b) {
  asm("v_mfma_f32_16x16x32_bf16 %0, %1, %2, %0" : "+v"(acc) : "v"(a), "a"(b));
}
__device__ __forceinline__ void mfma_v(f32x4& acc, short8 a, short8 b) {
  asm("v_mfma_f32_16x16x32_bf16 %0, %1, %2, %0" : "+v"(acc) : "v"(a), "v"(b));
}
// IC-coherent accesses (round-4 proven): per-instruction scope bits, no cache-wide fences
__device__ __forceinline__ short8 ld16_ic(const unsigned short* p) {
  union { unsigned long long q[2]; short8 v; } u;
  u.q[0] = __hip_atomic_load((const unsigned long long*)p, __ATOMIC_RELAXED, __HIP_MEMORY_SCOPE_AGENT);
  u.q[1] = __hip_atomic_load(((const unsigned long long*)p) + 1, __ATOMIC_RELAXED, __HIP_MEMORY_SCOPE_AGENT);
  return u.v;
}
__device__ __forceinline__ void st2_ic(unsigned short* p, unsigned short v) {
  unsigned int vv = v;
  asm volatile("global_store_short %0, %1, off sc0 sc1" :: "v"(p), "v"(vv) : "memory");
}
__device__ __forceinline__ void vmcnt0() { asm volatile("s_waitcnt vmcnt(0)" ::: "memory"); }
// wave-collective poll over per-lane (flag index, target); flags padded x16 ints
__device__ __forceinline__ void waitN(int* f, int idx, int tgt) {
  for (;;) {
    int v = __hip_atomic_load(&f[idx * 16], __ATOMIC_RELAXED, __HIP_MEMORY_SCOPE_AGENT);
    if (__all(v >= tgt)) break;
    __builtin_amdgcn_s_sleep(1);
  }
}

// ---------------- prep: weight bf16 conversion, bias sums, zero flags ----------------
__global__ void prep_kernel(const float* __restrict__ whh0, const float* __restrict__ wih1,
                            const float* __restrict__ whh1,
                            const float* __restrict__ bih0, const float* __restrict__ bhh0,
                            const float* __restrict__ bih1, const float* __restrict__ bhh1,
                            unsigned short* __restrict__ whh0b, unsigned short* __restrict__ wih1b,
                            unsigned short* __restrict__ whh1b,
                            float* __restrict__ bsum0, float* __restrict__ bsum1,
                            int* __restrict__ flags) {
  int i = blockIdx.x * blockDim.x + threadIdx.x;   // 262144 threads exactly
  if (i < 262144) {
    whh0b[i] = f2bf(whh0[i]);
    wih1b[i] = f2bf(wih1[i]);
    whh1b[i] = f2bf(whh1[i]);
  }
  if (i < 1024) bsum0[i] = bih0[i] + bhh0[i];
  else if (i < 2048) { int j = i - 1024; bsum1[j] = bih1[j] + bhh1[j]; }
  if (i < 8192) flags[i] = 0;
}

// ---------------- fused 2-stage pipeline, quarter-split, one launch, no LDS ----------------
// blocks 0-31: L0 (q*8+bg, 64 units each); blocks 32-63: L1 (q*8+bg, 64 units each).
// 256 threads (4 waves) per WG at 1 wave/SIMD -> 512-reg/lane budget.
// L0: whh0-quarter in AGPR. L1: whh1-quarter in AGPR + wih1-quarter in VGPR; computes
// xg = W_ih1.h1(t) and recurrence in ONE f32 accumulator (xg never touches memory).
// One flag per WG (value = steps completed), published after vmcnt0-all-waves + barrier.
// Waits (r4 semantics): data tgt=t/t+1; h1ring credit tgt=t at 8-step boundaries.
__attribute__((amdgpu_flat_work_group_size(256, 256)))
__attribute__((amdgpu_waves_per_eu(1, 1)))
__global__ void rec_all(
    const float* __restrict__ x,
    const unsigned short* __restrict__ whh0b, const float* __restrict__ wih0,
    const float* __restrict__ bsum0,
    const unsigned short* __restrict__ wih1b,
    const unsigned short* __restrict__ whh1b, const float* __restrict__ bsum1,
    const int* __restrict__ lengths,
    float* __restrict__ pooled,
    unsigned short* __restrict__ h1ring,   // [8][128][256] bf16
    unsigned short* __restrict__ h2ring,   // [2][128][256] bf16
    int* flags)
{
  const int tid = threadIdx.x;
  const int lane = tid & 63;
  const int w = tid >> 6;                  // 0..3
  const int l15 = lane & 15, l4 = lane >> 4;
  const int isL1 = (blockIdx.x >= 32);
  const int wg = blockIdx.x & 31;
  const int q = wg >> 3;
  const int bg = wg & 7;
  const int b0 = bg * 16;
  const int unit = q * 64 + w * 16 + l15;  // this WG's quarter
  const int myflag = blockIdx.x;

  // recurrent weights (AGPR-resident): rows gt*256+unit, K-cols kk*32+l4*8
  const unsigned short* WH = isL1 ? whh1b : whh0b;
  short8 wfh[4][8];
#pragma unroll
  for (int gt = 0; gt < 4; ++gt)
#pragma unroll
    for (int kk = 0; kk < 8; ++kk)
      wfh[gt][kk] = *(const short8*)(WH + (size_t)(gt * 256 + unit) * 256 + kk * 32 + l4 * 8);
  // input weights for L1 (VGPR-resident), same row map
  short8 wfi[4][8];
  if (isL1) {
#pragma unroll
    for (int gt = 0; gt < 4; ++gt)
#pragma unroll
      for (int kk = 0; kk < 8; ++kk)
        wfi[gt][kk] = *(const short8*)(wih1b + (size_t)(gt * 256 + unit) * 256 + kk * 32 + l4 * 8);
  }
  float bs_l[4], wih0_l[4];
#pragma unroll
  for (int gt = 0; gt < 4; ++gt) {
    bs_l[gt] = (isL1 ? bsum1 : bsum0)[gt * 256 + unit];
    wih0_l[gt] = isL1 ? 0.0f : wih0[gt * 256 + unit];
  }

  float c_[4] = {0.f, 0.f, 0.f, 0.f};
  float psum[4] = {0.f, 0.f, 0.f, 0.f};
  int len_[4];
#pragma unroll
  for (int r = 0; r < 4; ++r) len_[r] = lengths[b0 + l4 * 4 + r];

  for (int t = 0; t < TT; ++t) {
    // ---- waits (per-lane roles, single merged poll) ----
    {
      int idx = myflag, tgt = 0;
      if (isL1) {
        if (lane < 4) { idx = lane * 8 + bg; tgt = t + 1; }                       // h1(t): 4 L0 WGs
        else if (lane < 7) { idx = 32 + ((q + (lane - 3)) & 3) * 8 + bg; tgt = t; } // siblings h2(t-1)
      } else {
        if (lane < 3) { if (t > 0) { idx = ((q + lane + 1) & 3) * 8 + bg; tgt = t; } } // siblings h1(t-1)
        else if (lane < 7) { idx = 32 + (lane - 3) * 8 + bg;                      // L1 h1ring credit
                             tgt = ((t & 7) == 0 && t >= 8) ? t : 0; }
      }
      waitN(flags, idx, tgt);
    }

    f32x4 z = {0.f, 0.f, 0.f, 0.f};
    f32x4 acc[4];
#pragma unroll
    for (int gt = 0; gt < 4; ++gt) acc[gt] = z;

    if (isL1) {
      // xg contribution: A = h1(t) [slot t&7], B = wih1-quarter (VGPR)
      const unsigned short* hrow = h1ring + ((size_t)(t & 7) * BB + b0 + l15) * HH;
      short8 af[8];
#pragma unroll
      for (int kk = 0; kk < 8; ++kk) af[kk] = ld16_ic(hrow + kk * 32 + l4 * 8);
#pragma unroll
      for (int gt = 0; gt < 4; ++gt)
#pragma unroll
        for (int kk = 0; kk < 8; ++kk) mfma_v(acc[gt], af[kk], wfi[gt][kk]);
    }
    if (t > 0) {
      // recurrent contribution: A = h(t-1) of own layer, B = whh-quarter (AGPR)
      const unsigned short* hrow = isL1
          ? h2ring + ((size_t)((t - 1) & 1) * BB + b0 + l15) * HH
          : h1ring + ((size_t)((t - 1) & 7) * BB + b0 + l15) * HH;
      short8 af[8];
#pragma unroll
      for (int kk = 0; kk < 8; ++kk) af[kk] = ld16_ic(hrow + kk * 32 + l4 * 8);
#pragma unroll
      for (int gt = 0; gt < 4; ++gt)
#pragma unroll
        for (int kk = 0; kk < 8; ++kk) mfma_a(acc[gt], af[kk], wfh[gt][kk]);
    }

#pragma unroll
    for (int r = 0; r < 4; ++r) {
      const int sr = l4 * 4 + r;
      const int b = b0 + sr;
      float pre[4];
#pragma unroll
      for (int gt = 0; gt < 4; ++gt) pre[gt] = acc[gt][r] + bs_l[gt];
      if (!isL1) {
        const float xv = x[(size_t)b * TT + t];
#pragma unroll
        for (int gt = 0; gt < 4; ++gt) pre[gt] += xv * wih0_l[gt];
      }
      const float ig = sigm(pre[0]), fg = sigm(pre[1]), gg = tanh_f(pre[2]), og = sigm(pre[3]);
      const float cn = fg * c_[r] + ig * gg;
      c_[r] = cn;
      const float hn = og * tanh_f(cn);
      const unsigned short hb = f2bf(hn);
      if (!isL1) {
        st2_ic(&h1ring[((size_t)(t & 7) * BB + b0 + sr) * HH + unit], hb);
      } else {
        st2_ic(&h2ring[((size_t)(t & 1) * BB + b0 + sr) * HH + unit], hb);
        if (t < len_[r]) psum[r] += hn;
      }
    }
    vmcnt0();                 // this wave's stores at IC
    __syncthreads();          // => ALL waves' stores at IC
    if (tid == 0)
      __hip_atomic_store(&flags[myflag * 16], t + 1, __ATOMIC_RELAXED, __HIP_MEMORY_SCOPE_AGENT);
  }

  if (isL1) {
#pragma unroll
    for (int r = 0; r < 4; ++r)
      pooled[(size_t)(b0 + l4 * 4 + r) * HH + unit] = psum[r];
  }
}

// ---------------- epilogue: apply 1/len and linear head ----------------
__global__ void out_kernel(const float* __restrict__ pooled, const int* __restrict__ lengths,
                           const float* __restrict__ wlin, const float* __restrict__ blin,
                           float* __restrict__ out) {
  const int b = blockIdx.x;
  const int lane = threadIdx.x;   // 64
  float s[7];
#pragma unroll
  for (int c = 0; c < 7; ++c) s[c] = 0.f;
  for (int k = lane; k < 256; k += 64) {
    const float pv = pooled[b * 256 + k];
#pragma unroll
    for (int c = 0; c < 7; ++c) s[c] += pv * wlin[c * 256 + k];
  }
#pragma unroll
  for (int c = 0; c < 7; ++c) {
#pragma unroll
    for (int off = 32; off > 0; off >>= 1) s[c] += __shfl_down(s[c], off);
  }
  if (lane == 0) {
    const float inv = 1.0f / (float)lengths[b];
#pragma unroll
    for (int c = 0; c < 7; ++c) out[b * 7 + c] = s[c] * inv + blin[c];
  }
}

extern "C" void kernel_launch(void* const* d_in, const int* in_sizes, int n_in,
                              void* d_out, int out_size, void* d_ws, size_t ws_size,
                              hipStream_t stream) {
  const float* x      = (const float*)d_in[0];
  const int*   lengths= (const int*)d_in[1];
  const float* W_ih0  = (const float*)d_in[2];
  const float* W_hh0  = (const float*)d_in[3];
  const float* b_ih0  = (const float*)d_in[4];
  const float* b_hh0  = (const float*)d_in[5];
  const float* W_ih1  = (const float*)d_in[6];
  const float* W_hh1  = (const float*)d_in[7];
  const float* b_ih1  = (const float*)d_in[8];
  const float* b_hh1  = (const float*)d_in[9];
  const float* W_lin  = (const float*)d_in[10];
  const float* b_lin  = (const float*)d_in[11];
  float* out = (float*)d_out;

  char* ws = (char*)d_ws;
  unsigned short* whh0b = (unsigned short*)(ws + 0);
  unsigned short* wih1b = (unsigned short*)(ws + 524288);
  unsigned short* whh1b = (unsigned short*)(ws + 1048576);
  float* bsum0   = (float*)(ws + 1572864);
  float* bsum1   = (float*)(ws + 1576960);
  int*   flags   = (int*)  (ws + 1581056);                    // 8192 ints (padded flags)
  float* pooled  = (float*)(ws + 1613824);                    // 128KB
  unsigned short* h2ring = (unsigned short*)(ws + 1744896);   // 128KB
  unsigned short* h1ring = (unsigned short*)(ws + 1875968);   // 512KB

  prep_kernel<<<dim3(1024), dim3(256), 0, stream>>>(
      W_hh0, W_ih1, W_hh1, b_ih0, b_hh0, b_ih1, b_hh1,
      whh0b, wih1b, whh1b, bsum0, bsum1, flags);

  rec_all<<<dim3(64), dim3(256), 0, stream>>>(
      x, whh0b, W_ih0, bsum0, wih1b, whh1b, bsum1, lengths,
      pooled, h1ring, h2ring, flags);

  out_kernel<<<dim3(128), dim3(64), 0, stream>>>(pooled, lengths, W_lin, b_lin, out);
}